// Round 6
// baseline (3769.818 us; speedup 1.0000x reference)
//
#include <hip/hip_runtime.h>
#include <hip/hip_cooperative_groups.h>
namespace cg = cooperative_groups;

// SparseAffinity_Propagate: CSPN-style 8-neighbor propagation, 24 iterations.
// B=8, H=W=768. Offsets (dy,dx): (-5,0)(-1,0)(0,5)(0,1)(5,0)(1,0)(0,-5)(0,-1)
//
// Fusion (R0): result = sum_c (A*w_c) * prev[p+off_c] + Bias
// R1: weights fp16 AoS (16 B/px), bias fp32.
// R2: 4 px/thread vectorized (neutral -> not issue-bound).
// R3/R4: NT loads regressed; revert. Steps pinned at 35.8 us = 3.7 TB/s
//   effective -- SLOWER than a pure HBM stream (fills hit 7 TB/s). Diagnosis:
//   per-dispatch L2 invalidation forces the full 132 MB working set through
//   L3/HBM every step. Structural fix (R5): ONE persistent cooperative kernel,
//   weights/bias pinned in registers, state in LDS, only 5-row halo bands
//   exchanged through global memory per step (15.7 MB vs 132 MB), grid.sync
//   between steps.

#define HH 768
#define WW 768
#define BATCH 8
#define PLANE (HH * WW)           // 589824
#define TOTAL (BATCH * PLANE)     // 4718592
#define NITER 24

#define DYS {-5, -1, 0, 0, 5, 1, 0, 0}
#define DXS {0, 0, 5, 1, 0, 0, -5, -1}

// persistent-kernel tiling
#define TROWS 24                  // rows per block
#define TPB   32                  // tiles per batch (768/24)
#define NBLK  (BATCH * TPB)       // 256 blocks = 1/CU
#define BT    1024                // threads per block
#define PXPT  ((TROWS * WW) / BT) // 18 px per thread
#define LROWS (TROWS + 10)        // 34 LDS rows (5-row halo each side)
#define LSTR  (WW + 16)           // 784: 5 pad + 768 + 5 pad + 6 align
#define HALO_STRIDE (10 * WW)     // floats per block in halo buffer

typedef _Float16 half8 __attribute__((ext_vector_type(8)));
typedef float f4 __attribute__((ext_vector_type(4)));

__device__ __forceinline__ f4 ldf4(const float* p) { return *(const f4*)p; }

// ---------------------------------------------------------------------------
// Precompute pre-scaled weights (fp16 AoS, 16 B/px) + fp32 bias.
// Block = 192 threads = one row (4 px/thread). Grid (1, 768, 8).
// ---------------------------------------------------------------------------
__global__ __launch_bounds__(192) void precompute_kernel(
    const float* __restrict__ g,       // (B,8,H,W)
    const float* __restrict__ blur,    // (B,1,H,W)
    const float* __restrict__ sparse,  // (B,1,H,W)
    half8* __restrict__ wout,          // (B*H*W) x 8 fp16  (AoS)
    float* __restrict__ bias)          // (B*H*W)
{
    const int x0 = 4 * threadIdx.x;
    const int y  = blockIdx.y;
    const int b  = blockIdx.z;
    const float* gb = g + (size_t)b * 8 * PLANE;
    const int rowb = y * WW;
    const int pidx = b * PLANE + rowb + x0;

    f4 wv[8];
    if (x0 >= 8 && x0 <= 756) {
        const f4 zero = (f4)0.f;
        wv[0] = (y >= 5)      ? ldf4(gb + 0 * PLANE + (y - 5) * WW + x0) : zero;
        wv[1] = (y >= 1)      ? ldf4(gb + 1 * PLANE + (y - 1) * WW + x0) : zero;
        wv[4] = (y <= HH - 6) ? ldf4(gb + 4 * PLANE + (y + 5) * WW + x0) : zero;
        wv[5] = (y <= HH - 2) ? ldf4(gb + 5 * PLANE + (y + 1) * WW + x0) : zero;
        {   // c=2, dx=+5
            f4 a = ldf4(gb + 2 * PLANE + rowb + x0 + 4);
            f4 bq = ldf4(gb + 2 * PLANE + rowb + x0 + 8);
            wv[2] = f4{a[1], a[2], a[3], bq[0]};
        }
        {   // c=3, dx=+1
            f4 a = ldf4(gb + 3 * PLANE + rowb + x0);
            f4 bq = ldf4(gb + 3 * PLANE + rowb + x0 + 4);
            wv[3] = f4{a[1], a[2], a[3], bq[0]};
        }
        {   // c=6, dx=-5
            f4 a = ldf4(gb + 6 * PLANE + rowb + x0 - 8);
            f4 bq = ldf4(gb + 6 * PLANE + rowb + x0 - 4);
            wv[6] = f4{a[3], bq[0], bq[1], bq[2]};
        }
        {   // c=7, dx=-1
            f4 a = ldf4(gb + 7 * PLANE + rowb + x0 - 4);
            f4 bq = ldf4(gb + 7 * PLANE + rowb + x0);
            wv[7] = f4{a[3], bq[0], bq[1], bq[2]};
        }
    } else {
        const int dy[8] = DYS;
        const int dx[8] = DXS;
#pragma unroll
        for (int c = 0; c < 8; ++c) {
#pragma unroll
            for (int j = 0; j < 4; ++j) {
                int yy = y + dy[c];
                int xx = x0 + j + dx[c];
                float v = 0.f;
                if (yy >= 0 && yy < HH && xx >= 0 && xx < WW)
                    v = gb[c * PLANE + yy * WW + xx];
                wv[c][j] = v;
            }
        }
    }

    f4 raw = ldf4(blur + pidx);
    f4 sd  = ldf4(sparse + pidx);
    f4 bout;
#pragma unroll
    for (int j = 0; j < 4; ++j) {
        float abssum = 0.f;
#pragma unroll
        for (int c = 0; c < 8; ++c) abssum += fabsf(wv[c][j]);
        float inv = 1.f / fmaxf(abssum, 1e-6f);
        float gs = 0.f;
#pragma unroll
        for (int c = 0; c < 8; ++c) gs += wv[c][j] * inv;
        float s = sd[j];
        float m = (s > 0.f) ? 1.f : ((s < 0.f) ? -1.f : 0.f);
        float A = 1.f - m;
        bout[j] = (A * (1.f - gs) + m) * raw[j];
        float Ai = A * inv;
        half8 hv;
#pragma unroll
        for (int c = 0; c < 8; ++c) hv[c] = (_Float16)(Ai * wv[c][j]);
        wout[pidx + j] = hv;
    }
    *(f4*)(bias + pidx) = bout;
}

// ---------------------------------------------------------------------------
// Persistent propagation kernel: all 24 steps in one cooperative launch.
// 256 blocks x 1024 threads; block bb owns rows [y0, y0+23] of batch bb>>5.
// State in LDS (34 rows x 784, zero-padded borders). Per step, only the
// 5-row edge bands go through global halo buffers (parity double-buffered).
// ---------------------------------------------------------------------------
__global__ __launch_bounds__(BT) void persist_kernel(
    const half8* __restrict__ w,     // (B*H*W) x 8 fp16
    const float* __restrict__ bias,  // (B*H*W)
    const float* __restrict__ blur,  // (B,H,W)  initial state
    float* __restrict__ haloA,       // NBLK * 10*WW floats
    float* __restrict__ haloB,       // NBLK * 10*WW floats
    float* __restrict__ out)         // (B,H,W)
{
    __shared__ float tile[LROWS * LSTR];   // 106,624 B
    cg::grid_group grid = cg::this_grid();

    const int tid = threadIdx.x;
    const int bb  = blockIdx.x;
    const int b   = bb >> 5;
    const int ty  = bb & 31;
    const int y0  = ty * TROWS;
    const int base = b * PLANE + y0 * WW;  // global px index of tile origin

    // ---- init: zero LDS (x/y halo pads stay 0 forever) ----
    for (int i = tid; i < LROWS * LSTR; i += BT) tile[i] = 0.f;
    __syncthreads();
    // ---- init: state0 = blur over rows [y0-5, y0+28] (in-image only) ----
    for (int i = tid; i < LROWS * WW; i += BT) {
        int r = i / WW;            // 0..33
        int c = i - r * WW;
        int gy = y0 + r - 5;
        if (gy >= 0 && gy < HH)
            tile[r * LSTR + c + 5] = blur[b * PLANE + gy * WW + c];
    }
    // ---- init: pin weights + bias in registers (coalesced) ----
    half8 wv[PXPT];
    float bv[PXPT];
#pragma unroll
    for (int k = 0; k < PXPT; ++k) {
        wv[k] = w[base + tid + k * BT];
        bv[k] = bias[base + tid + k * BT];
    }
    __syncthreads();

    float* halos[2] = {haloA, haloB};

    for (int s = 0; s < NITER; ++s) {
        // ---- pull neighbor halo bands (written by them last step) ----
        if (s > 0) {
            const float* hsrc = halos[s & 1];
            if (ty > 0) {
                const float* src = hsrc + (size_t)(bb - 1) * HALO_STRIDE + 5 * WW;
                for (int i = tid; i < 5 * WW; i += BT) {
                    int r = i / WW, c = i - r * WW;
                    tile[r * LSTR + c + 5] = src[i];          // LDS rows 0..4
                }
            }
            if (ty < TPB - 1) {
                const float* src = hsrc + (size_t)(bb + 1) * HALO_STRIDE;
                for (int i = tid; i < 5 * WW; i += BT) {
                    int r = i / WW, c = i - r * WW;
                    tile[(29 + r) * LSTR + c + 5] = src[i];   // LDS rows 29..33
                }
            }
        }
        __syncthreads();

        // ---- compute 18 px/thread from LDS (no guards: pads are zero) ----
        float nv[PXPT];
#pragma unroll
        for (int k = 0; k < PXPT; ++k) {
            int j   = tid + k * BT;
            int row = j / WW;
            int col = j - row * WW;
            int idx = (row + 5) * LSTR + col + 5;
            float acc = bv[k];
            acc = fmaf((float)wv[k][0], tile[idx - 5 * LSTR], acc);  // (-5,0)
            acc = fmaf((float)wv[k][1], tile[idx - LSTR],     acc);  // (-1,0)
            acc = fmaf((float)wv[k][2], tile[idx + 5],        acc);  // (0,+5)
            acc = fmaf((float)wv[k][3], tile[idx + 1],        acc);  // (0,+1)
            acc = fmaf((float)wv[k][4], tile[idx + 5 * LSTR], acc);  // (+5,0)
            acc = fmaf((float)wv[k][5], tile[idx + LSTR],     acc);  // (+1,0)
            acc = fmaf((float)wv[k][6], tile[idx - 5],        acc);  // (0,-5)
            acc = fmaf((float)wv[k][7], tile[idx - 1],        acc);  // (0,-1)
            nv[k] = acc;
        }
        __syncthreads();   // all reads of state s done before overwrite

        if (s == NITER - 1) {
            // final: write full tile to out (nobody reads it -> no race)
#pragma unroll
            for (int k = 0; k < PXPT; ++k)
                out[base + tid + k * BT] = nv[k];
        } else {
            float* hdst = halos[(s + 1) & 1] + (size_t)bb * HALO_STRIDE;
#pragma unroll
            for (int k = 0; k < PXPT; ++k) {
                int j   = tid + k * BT;
                int row = j / WW;
                int col = j - row * WW;
                tile[(row + 5) * LSTR + col + 5] = nv[k];
                if (row < 5)
                    hdst[j] = nv[k];                 // top band slots 0..4
                else if (row >= TROWS - 5)
                    hdst[j - 14 * WW] = nv[k];       // bottom band slots 5..9
            }
            __threadfence();   // device-scope visibility of halo stores
            grid.sync();       // uniform across all blocks (s is uniform)
        }
    }
}

// ---------------------------------------------------------------------------
// Fallback step (small ws): recompute weights/bias from inputs every step.
// ---------------------------------------------------------------------------
__global__ __launch_bounds__(256) void step_recompute_kernel(
    const float* __restrict__ g,
    const float* __restrict__ blur,
    const float* __restrict__ sparse,
    const float* __restrict__ prev,
    float* __restrict__ next)
{
    const int dy[8] = DYS;
    const int dx[8] = DXS;
    int x = blockIdx.x * blockDim.x + threadIdx.x;
    int y = blockIdx.y;
    int b = blockIdx.z;
    if (x >= WW) return;

    const float* gb = g + (size_t)b * 8 * PLANE;
    float w[8];
    float abssum = 0.f;
#pragma unroll
    for (int c = 0; c < 8; ++c) {
        int yy = y + dy[c];
        int xx = x + dx[c];
        float v = 0.f;
        if (yy >= 0 && yy < HH && xx >= 0 && xx < WW)
            v = gb[c * PLANE + yy * WW + xx];
        w[c] = v;
        abssum += fabsf(v);
    }
    float inv = 1.f / fmaxf(abssum, 1e-6f);
    float gs = 0.f;
#pragma unroll
    for (int c = 0; c < 8; ++c) {
        w[c] *= inv;
        gs += w[c];
    }
    int pidx = b * PLANE + y * WW + x;
    float sd = sparse[pidx];
    float m = (sd > 0.f) ? 1.f : ((sd < 0.f) ? -1.f : 0.f);
    float A = 1.f - m;
    float raw = blur[pidx];

    const float* pb = prev + b * PLANE;
    float acc = 0.f;
#pragma unroll
    for (int c = 0; c < 8; ++c) {
        int yy = y + dy[c];
        int xx = x + dx[c];
        float n = 0.f;
        if (yy >= 0 && yy < HH && xx >= 0 && xx < WW)
            n = pb[yy * WW + xx];
        acc = fmaf(A * w[c], n, acc);
    }
    next[pidx] = acc + (A * (1.f - gs) + m) * raw;
}

// ---------------------------------------------------------------------------
extern "C" void kernel_launch(void* const* d_in, const int* in_sizes, int n_in,
                              void* d_out, int out_size, void* d_ws, size_t ws_size,
                              hipStream_t stream) {
    const float* g      = (const float*)d_in[0];  // guidance (B,8,H,W)
    const float* blur   = (const float*)d_in[1];  // blur_depth (B,1,H,W)
    const float* sparse = (const float*)d_in[2];  // sparse_depth (B,1,H,W)
    float* out = (float*)d_out;

    // ws layout: w (16 B/px) | bias (4 B/px) | haloA | haloB
    const size_t w_bytes    = (size_t)TOTAL * 16;
    const size_t bias_bytes = (size_t)TOTAL * 4;
    const size_t halo_bytes = (size_t)NBLK * HALO_STRIDE * 4;  // 7.86 MB
    const size_t need_fast  = w_bytes + bias_bytes + 2 * halo_bytes;  // ~110 MB

    if (ws_size >= need_fast) {
        half8* w     = (half8*)d_ws;
        float* bias  = (float*)((char*)d_ws + w_bytes);
        float* haloA = (float*)((char*)d_ws + w_bytes + bias_bytes);
        float* haloB = (float*)((char*)d_ws + w_bytes + bias_bytes + halo_bytes);

        dim3 blockP(192, 1, 1);
        dim3 gridP(1, HH, BATCH);
        precompute_kernel<<<gridP, blockP, 0, stream>>>(g, blur, sparse, w, bias);

        const half8* wc    = w;
        const float* biasc = bias;
        const float* blurc = blur;
        void* args[6] = {(void*)&wc, (void*)&biasc, (void*)&blurc,
                         (void*)&haloA, (void*)&haloB, (void*)&out};
        hipLaunchCooperativeKernel((void*)persist_kernel, dim3(NBLK), dim3(BT),
                                   args, 0, stream);
    } else {
        // Fallback: only one ping buffer in ws; recompute weights each step.
        dim3 block2(256, 1, 1);
        dim3 grid2(WW / 256, HH, BATCH);
        float* r0 = (float*)d_ws;
        const float* prev = blur;
        for (int it = 0; it < NITER; ++it) {
            float* nxt = (it % 2 == 0) ? r0 : out;
            step_recompute_kernel<<<grid2, block2, 0, stream>>>(g, blur, sparse,
                                                                prev, nxt);
            prev = nxt;
        }
    }
}

// Round 7
// 3459.836 us; speedup vs baseline: 1.0896x; 1.0896x over previous
//
#include <hip/hip_runtime.h>
#include <hip/hip_cooperative_groups.h>
namespace cg = cooperative_groups;

// SparseAffinity_Propagate: CSPN-style 8-neighbor propagation, 24 iterations.
// B=8, H=W=768. Offsets (dy,dx): (-5,0)(-1,0)(0,5)(0,1)(5,0)(1,0)(0,-5)(0,-1)
//
// Fusion (R0): result = sum_c (A*w_c) * prev[p+off_c] + Bias
// R1: weights fp16 AoS (16 B/px), bias fp32.
// R5: persistent cooperative kernel, state in LDS, 5-row halo exchange.
// R6 post-mortem: compiler capped VGPR at 64 (no min-occupancy floor) and
//   spilled wv/bv/nv -> 1.49 GB scratch traffic, 3.5 ms. Fix (R7):
//   __launch_bounds__(1024, 4) raises the VGPR cap to 128 (4 waves/EU =
//   our actual 1 block/CU), and bias is STREAMED per step (L2-warm inside
//   the persistent kernel) instead of pinned: wv 72 + nv 18 + addr ~20 < 128.

#define HH 768
#define WW 768
#define BATCH 8
#define PLANE (HH * WW)           // 589824
#define TOTAL (BATCH * PLANE)     // 4718592
#define NITER 24

#define DYS {-5, -1, 0, 0, 5, 1, 0, 0}
#define DXS {0, 0, 5, 1, 0, 0, -5, -1}

// persistent-kernel tiling
#define TROWS 24                  // rows per block
#define TPB   32                  // tiles per batch (768/24)
#define NBLK  (BATCH * TPB)       // 256 blocks = 1/CU
#define BT    1024                // threads per block
#define PXPT  ((TROWS * WW) / BT) // 18 px per thread
#define LROWS (TROWS + 10)        // 34 LDS rows (5-row halo each side)
#define LSTR  (WW + 16)           // 784: 5 pad + 768 + 5 pad + 6 align
#define HALO_STRIDE (10 * WW)     // floats per block in halo buffer

typedef _Float16 half8 __attribute__((ext_vector_type(8)));
typedef float f4 __attribute__((ext_vector_type(4)));

__device__ __forceinline__ f4 ldf4(const float* p) { return *(const f4*)p; }

// ---------------------------------------------------------------------------
// Precompute pre-scaled weights (fp16 AoS, 16 B/px) + fp32 bias.
// Block = 192 threads = one row (4 px/thread). Grid (1, 768, 8).
// ---------------------------------------------------------------------------
__global__ __launch_bounds__(192) void precompute_kernel(
    const float* __restrict__ g,       // (B,8,H,W)
    const float* __restrict__ blur,    // (B,1,H,W)
    const float* __restrict__ sparse,  // (B,1,H,W)
    half8* __restrict__ wout,          // (B*H*W) x 8 fp16  (AoS)
    float* __restrict__ bias)          // (B*H*W)
{
    const int x0 = 4 * threadIdx.x;
    const int y  = blockIdx.y;
    const int b  = blockIdx.z;
    const float* gb = g + (size_t)b * 8 * PLANE;
    const int rowb = y * WW;
    const int pidx = b * PLANE + rowb + x0;

    f4 wv[8];
    if (x0 >= 8 && x0 <= 756) {
        const f4 zero = (f4)0.f;
        wv[0] = (y >= 5)      ? ldf4(gb + 0 * PLANE + (y - 5) * WW + x0) : zero;
        wv[1] = (y >= 1)      ? ldf4(gb + 1 * PLANE + (y - 1) * WW + x0) : zero;
        wv[4] = (y <= HH - 6) ? ldf4(gb + 4 * PLANE + (y + 5) * WW + x0) : zero;
        wv[5] = (y <= HH - 2) ? ldf4(gb + 5 * PLANE + (y + 1) * WW + x0) : zero;
        {   // c=2, dx=+5
            f4 a = ldf4(gb + 2 * PLANE + rowb + x0 + 4);
            f4 bq = ldf4(gb + 2 * PLANE + rowb + x0 + 8);
            wv[2] = f4{a[1], a[2], a[3], bq[0]};
        }
        {   // c=3, dx=+1
            f4 a = ldf4(gb + 3 * PLANE + rowb + x0);
            f4 bq = ldf4(gb + 3 * PLANE + rowb + x0 + 4);
            wv[3] = f4{a[1], a[2], a[3], bq[0]};
        }
        {   // c=6, dx=-5
            f4 a = ldf4(gb + 6 * PLANE + rowb + x0 - 8);
            f4 bq = ldf4(gb + 6 * PLANE + rowb + x0 - 4);
            wv[6] = f4{a[3], bq[0], bq[1], bq[2]};
        }
        {   // c=7, dx=-1
            f4 a = ldf4(gb + 7 * PLANE + rowb + x0 - 4);
            f4 bq = ldf4(gb + 7 * PLANE + rowb + x0);
            wv[7] = f4{a[3], bq[0], bq[1], bq[2]};
        }
    } else {
        const int dy[8] = DYS;
        const int dx[8] = DXS;
#pragma unroll
        for (int c = 0; c < 8; ++c) {
#pragma unroll
            for (int j = 0; j < 4; ++j) {
                int yy = y + dy[c];
                int xx = x0 + j + dx[c];
                float v = 0.f;
                if (yy >= 0 && yy < HH && xx >= 0 && xx < WW)
                    v = gb[c * PLANE + yy * WW + xx];
                wv[c][j] = v;
            }
        }
    }

    f4 raw = ldf4(blur + pidx);
    f4 sd  = ldf4(sparse + pidx);
    f4 bout;
#pragma unroll
    for (int j = 0; j < 4; ++j) {
        float abssum = 0.f;
#pragma unroll
        for (int c = 0; c < 8; ++c) abssum += fabsf(wv[c][j]);
        float inv = 1.f / fmaxf(abssum, 1e-6f);
        float gs = 0.f;
#pragma unroll
        for (int c = 0; c < 8; ++c) gs += wv[c][j] * inv;
        float s = sd[j];
        float m = (s > 0.f) ? 1.f : ((s < 0.f) ? -1.f : 0.f);
        float A = 1.f - m;
        bout[j] = (A * (1.f - gs) + m) * raw[j];
        float Ai = A * inv;
        half8 hv;
#pragma unroll
        for (int c = 0; c < 8; ++c) hv[c] = (_Float16)(Ai * wv[c][j]);
        wout[pidx + j] = hv;
    }
    *(f4*)(bias + pidx) = bout;
}

// ---------------------------------------------------------------------------
// Persistent propagation kernel: all 24 steps in one cooperative launch.
// 256 blocks x 1024 threads; block bb owns rows [y0, y0+23] of batch bb>>5.
// State in LDS (34 rows x 784, zero-padded borders). Per step, only the
// 5-row edge bands go through global halo buffers (parity double-buffered).
// __launch_bounds__(1024, 4): 4 waves/EU floor -> VGPR cap 128 (R6 spilled
// at the default 64-cap). Weights pinned (72 VGPR); bias streamed per step.
// ---------------------------------------------------------------------------
__global__ __launch_bounds__(BT, 4) void persist_kernel(
    const half8* __restrict__ w,     // (B*H*W) x 8 fp16
    const float* __restrict__ bias,  // (B*H*W)
    const float* __restrict__ blur,  // (B,H,W)  initial state
    float* __restrict__ haloA,       // NBLK * 10*WW floats
    float* __restrict__ haloB,       // NBLK * 10*WW floats
    float* __restrict__ out)         // (B,H,W)
{
    __shared__ float tile[LROWS * LSTR];   // 106,624 B
    cg::grid_group grid = cg::this_grid();

    const int tid = threadIdx.x;
    const int bb  = blockIdx.x;
    const int b   = bb >> 5;
    const int ty  = bb & 31;
    const int y0  = ty * TROWS;
    const int base = b * PLANE + y0 * WW;  // global px index of tile origin

    // ---- init: zero LDS (x/y halo pads stay 0 forever) ----
    for (int i = tid; i < LROWS * LSTR; i += BT) tile[i] = 0.f;
    __syncthreads();
    // ---- init: state0 = blur over rows [y0-5, y0+28] (in-image only) ----
    for (int i = tid; i < LROWS * WW; i += BT) {
        int r = i / WW;            // 0..33
        int c = i - r * WW;
        int gy = y0 + r - 5;
        if (gy >= 0 && gy < HH)
            tile[r * LSTR + c + 5] = blur[b * PLANE + gy * WW + c];
    }
    // ---- init: pin weights in registers (72 VGPR, coalesced load) ----
    half8 wv[PXPT];
#pragma unroll
    for (int k = 0; k < PXPT; ++k)
        wv[k] = w[base + tid + k * BT];
    __syncthreads();

    for (int s = 0; s < NITER; ++s) {
        // ---- pull neighbor halo bands (written by them last step) ----
        if (s > 0) {
            const float* hsrc = (s & 1) ? haloB : haloA;
            if (ty > 0) {
                const float* src = hsrc + (size_t)(bb - 1) * HALO_STRIDE + 5 * WW;
                for (int i = tid; i < 5 * WW; i += BT) {
                    int r = i / WW, c = i - r * WW;
                    tile[r * LSTR + c + 5] = src[i];          // LDS rows 0..4
                }
            }
            if (ty < TPB - 1) {
                const float* src = hsrc + (size_t)(bb + 1) * HALO_STRIDE;
                for (int i = tid; i < 5 * WW; i += BT) {
                    int r = i / WW, c = i - r * WW;
                    tile[(29 + r) * LSTR + c + 5] = src[i];   // LDS rows 29..33
                }
            }
        }
        __syncthreads();

        // ---- compute 18 px/thread from LDS (no guards: pads are zero) ----
        // bias streamed from global: L2-warm after step 1 (no dispatch flush
        // inside a persistent kernel); saves 18 VGPRs vs pinning.
        float nv[PXPT];
#pragma unroll
        for (int k = 0; k < PXPT; ++k) {
            int j   = tid + k * BT;
            int row = j / WW;
            int col = j - row * WW;
            int idx = (row + 5) * LSTR + col + 5;
            float acc = bias[base + j];
            acc = fmaf((float)wv[k][0], tile[idx - 5 * LSTR], acc);  // (-5,0)
            acc = fmaf((float)wv[k][1], tile[idx - LSTR],     acc);  // (-1,0)
            acc = fmaf((float)wv[k][2], tile[idx + 5],        acc);  // (0,+5)
            acc = fmaf((float)wv[k][3], tile[idx + 1],        acc);  // (0,+1)
            acc = fmaf((float)wv[k][4], tile[idx + 5 * LSTR], acc);  // (+5,0)
            acc = fmaf((float)wv[k][5], tile[idx + LSTR],     acc);  // (+1,0)
            acc = fmaf((float)wv[k][6], tile[idx - 5],        acc);  // (0,-5)
            acc = fmaf((float)wv[k][7], tile[idx - 1],        acc);  // (0,-1)
            nv[k] = acc;
        }
        __syncthreads();   // all reads of state s done before overwrite

        if (s == NITER - 1) {
            // final: write full tile to out (nobody reads it -> no race)
#pragma unroll
            for (int k = 0; k < PXPT; ++k)
                out[base + tid + k * BT] = nv[k];
        } else {
            float* hdst = ((s + 1) & 1 ? haloB : haloA)
                          + (size_t)bb * HALO_STRIDE;
#pragma unroll
            for (int k = 0; k < PXPT; ++k) {
                int j   = tid + k * BT;
                int row = j / WW;
                int col = j - row * WW;
                tile[(row + 5) * LSTR + col + 5] = nv[k];
                if (row < 5)
                    hdst[j] = nv[k];                 // top band slots 0..4
                else if (row >= TROWS - 5)
                    hdst[j - 14 * WW] = nv[k];       // bottom band slots 5..9
            }
            __threadfence();   // device-scope visibility of halo stores
            grid.sync();       // uniform across all blocks (s is uniform)
        }
    }
}

// ---------------------------------------------------------------------------
// Fallback step (small ws): recompute weights/bias from inputs every step.
// ---------------------------------------------------------------------------
__global__ __launch_bounds__(256) void step_recompute_kernel(
    const float* __restrict__ g,
    const float* __restrict__ blur,
    const float* __restrict__ sparse,
    const float* __restrict__ prev,
    float* __restrict__ next)
{
    const int dy[8] = DYS;
    const int dx[8] = DXS;
    int x = blockIdx.x * blockDim.x + threadIdx.x;
    int y = blockIdx.y;
    int b = blockIdx.z;
    if (x >= WW) return;

    const float* gb = g + (size_t)b * 8 * PLANE;
    float w[8];
    float abssum = 0.f;
#pragma unroll
    for (int c = 0; c < 8; ++c) {
        int yy = y + dy[c];
        int xx = x + dx[c];
        float v = 0.f;
        if (yy >= 0 && yy < HH && xx >= 0 && xx < WW)
            v = gb[c * PLANE + yy * WW + xx];
        w[c] = v;
        abssum += fabsf(v);
    }
    float inv = 1.f / fmaxf(abssum, 1e-6f);
    float gs = 0.f;
#pragma unroll
    for (int c = 0; c < 8; ++c) {
        w[c] *= inv;
        gs += w[c];
    }
    int pidx = b * PLANE + y * WW + x;
    float sd = sparse[pidx];
    float m = (sd > 0.f) ? 1.f : ((sd < 0.f) ? -1.f : 0.f);
    float A = 1.f - m;
    float raw = blur[pidx];

    const float* pb = prev + b * PLANE;
    float acc = 0.f;
#pragma unroll
    for (int c = 0; c < 8; ++c) {
        int yy = y + dy[c];
        int xx = x + dx[c];
        float n = 0.f;
        if (yy >= 0 && yy < HH && xx >= 0 && xx < WW)
            n = pb[yy * WW + xx];
        acc = fmaf(A * w[c], n, acc);
    }
    next[pidx] = acc + (A * (1.f - gs) + m) * raw;
}

// ---------------------------------------------------------------------------
extern "C" void kernel_launch(void* const* d_in, const int* in_sizes, int n_in,
                              void* d_out, int out_size, void* d_ws, size_t ws_size,
                              hipStream_t stream) {
    const float* g      = (const float*)d_in[0];  // guidance (B,8,H,W)
    const float* blur   = (const float*)d_in[1];  // blur_depth (B,1,H,W)
    const float* sparse = (const float*)d_in[2];  // sparse_depth (B,1,H,W)
    float* out = (float*)d_out;

    // ws layout: w (16 B/px) | bias (4 B/px) | haloA | haloB
    const size_t w_bytes    = (size_t)TOTAL * 16;
    const size_t bias_bytes = (size_t)TOTAL * 4;
    const size_t halo_bytes = (size_t)NBLK * HALO_STRIDE * 4;  // 7.86 MB
    const size_t need_fast  = w_bytes + bias_bytes + 2 * halo_bytes;  // ~110 MB

    if (ws_size >= need_fast) {
        half8* w     = (half8*)d_ws;
        float* bias  = (float*)((char*)d_ws + w_bytes);
        float* haloA = (float*)((char*)d_ws + w_bytes + bias_bytes);
        float* haloB = (float*)((char*)d_ws + w_bytes + bias_bytes + halo_bytes);

        dim3 blockP(192, 1, 1);
        dim3 gridP(1, HH, BATCH);
        precompute_kernel<<<gridP, blockP, 0, stream>>>(g, blur, sparse, w, bias);

        const half8* wc    = w;
        const float* biasc = bias;
        const float* blurc = blur;
        void* args[6] = {(void*)&wc, (void*)&biasc, (void*)&blurc,
                         (void*)&haloA, (void*)&haloB, (void*)&out};
        hipLaunchCooperativeKernel((void*)persist_kernel, dim3(NBLK), dim3(BT),
                                   args, 0, stream);
    } else {
        // Fallback: only one ping buffer in ws; recompute weights each step.
        dim3 block2(256, 1, 1);
        dim3 grid2(WW / 256, HH, BATCH);
        float* r0 = (float*)d_ws;
        const float* prev = blur;
        for (int it = 0; it < NITER; ++it) {
            float* nxt = (it % 2 == 0) ? r0 : out;
            step_recompute_kernel<<<grid2, block2, 0, stream>>>(g, blur, sparse,
                                                                prev, nxt);
            prev = nxt;
        }
    }
}